// Round 5
// baseline (2927.961 us; speedup 1.0000x reference)
//
#include <hip/hip_runtime.h>
#include <hip/hip_bf16.h>

typedef __bf16 bf16x8 __attribute__((ext_vector_type(8)));
typedef __bf16 bf16x4 __attribute__((ext_vector_type(4)));
typedef float  f32x4  __attribute__((ext_vector_type(4)));
typedef unsigned int u32x2 __attribute__((ext_vector_type(2)));

#define T_STEPS 1024
#define LOG2E 1.4426950408889634f

// LDS-only barrier: orders ds ops across the workgroup WITHOUT the vmcnt(0)
// drain __syncthreads() emits; global loads/stores stay in flight.
#define LDS_BARRIER() asm volatile("s_waitcnt lgkmcnt(0)\n\ts_barrier" ::: "memory")

#define MFMA(a, b, c) __builtin_amdgcn_mfma_f32_16x16x32_bf16((a), (b), (c), 0, 0, 0)

__device__ __forceinline__ float fast_sigmoid(float x) {
  float e = __builtin_amdgcn_exp2f(x * -LOG2E);
  return __builtin_amdgcn_rcpf(1.f + e);
}
__device__ __forceinline__ float fast_tanh(float x) {
  float e = __builtin_amdgcn_exp2f(x * (2.f * LOG2E));
  return 1.f - 2.f * __builtin_amdgcn_rcpf(1.f + e);
}
// exact bf16(hi16-of-f32) -> f32 re-embedding, 1 VALU op each
__device__ __forceinline__ float bf_lo(unsigned int u) { return __uint_as_float(u << 16); }
__device__ __forceinline__ float bf_hi(unsigned int u) { return __uint_as_float(u & 0xFFFF0000u); }

// ws layout (all bf16):
//   afrag: [mat(6)][cb(16)][kblk(8)][lane(64)][j(8)]   (393216 elems)
//     mats: 0=W_z 1=W_r 2=W 3=U_z 4=U_r 5=U
//     content = M[k][col], k = kblk*32 + (lane>>4)*8 + j, col = cb*16 + (lane&15)
//   gates: [t*4+g][mat(3)][p(8)][lane(64)][c(2)][i(4)]  (50331648 elems)
//     mat 0=z,1=r,2=h; MFMA C-layout per colblock pair.

__global__ __launch_bounds__(256) void prep_frags(
    const float* __restrict__ Wz, const float* __restrict__ Wr, const float* __restrict__ Wh,
    const float* __restrict__ Uz, const float* __restrict__ Ur, const float* __restrict__ Uh,
    __bf16* __restrict__ afrag)
{
  int idx  = blockIdx.x * 256 + threadIdx.x;   // 1536*256 = 393216 exactly
  int mat  = idx >> 16;
  int cb   = (idx >> 12) & 15;
  int kblk = (idx >> 9) & 7;
  int l    = (idx >> 3) & 63;
  int j    = idx & 7;
  int k    = kblk * 32 + (l >> 4) * 8 + j;
  int col  = cb * 16 + (l & 15);
  const float* s = (mat == 0) ? Wz : (mat == 1) ? Wr : (mat == 2) ? Wh
                 : (mat == 3) ? Uz : (mat == 4) ? Ur : Uh;
  afrag[idx] = (__bf16)s[k * 256 + col];
}

// X-projection GEMM: block = one timestep t (1024 blocks, 4 waves).
__global__ __launch_bounds__(256) void gemm_x(
    const float* __restrict__ x, const __bf16* __restrict__ afrag,
    const float* __restrict__ bz, const float* __restrict__ br, const float* __restrict__ bh,
    __bf16* __restrict__ gates)
{
  int t = blockIdx.x;                  // timestep
  int tid = threadIdx.x;
  int l = tid & 63, w = tid >> 6;
  int q = l >> 4, m15 = l & 15;

  bf16x8 bfr[4][8];
#pragma unroll
  for (int g = 0; g < 4; g++) {
    const float* xrow = x + ((size_t)t * 64 + g * 16 + m15) * 256 + q * 8;
#pragma unroll
    for (int kb = 0; kb < 8; kb++) {
      f32x4 lo = *(const f32x4*)(xrow + kb * 32);
      f32x4 hi = *(const f32x4*)(xrow + kb * 32 + 4);
      bf16x8 v;
#pragma unroll
      for (int j = 0; j < 4; j++) { v[j] = (__bf16)lo[j]; v[4 + j] = (__bf16)hi[j]; }
      bfr[g][kb] = v;
    }
  }

  const bf16x8* af = (const bf16x8*)afrag;
#pragma unroll 1
  for (int jj = 0; jj < 12; jj++) {
    int nt = w + 4 * jj;
    int mat = nt >> 4, cb = nt & 15;
    f32x4 acc[4];
#pragma unroll
    for (int g = 0; g < 4; g++) acc[g] = (f32x4){0.f, 0.f, 0.f, 0.f};
#pragma unroll
    for (int kb = 0; kb < 8; kb++) {
      bf16x8 a = af[(nt * 8 + kb) * 64 + l];
#pragma unroll
      for (int g = 0; g < 4; g++)
        acc[g] = MFMA(a, bfr[g][kb], acc[g]);
    }
    const float* bias = (mat == 0) ? bz : (mat == 1) ? br : bh;
    float b4[4];
#pragma unroll
    for (int i = 0; i < 4; i++) b4[i] = bias[cb * 16 + q * 4 + i];
    int p = cb >> 1, c = cb & 1;
#pragma unroll
    for (int g = 0; g < 4; g++) {
      bf16x4 ov;
#pragma unroll
      for (int i = 0; i < 4; i++) ov[i] = (__bf16)(acc[g][i] + b4[i]);
      *(bf16x4*)(gates + ((size_t)t * 4 + g) * 12288 + ((mat * 8 + p) * 64 + l) * 8 + c * 4) = ov;
    }
  }
}

// Recurrent kernel: 4 blocks x 1024 threads (16 waves, 4 waves/SIMD).
// Wave w owns colblock w (16 features). wz/wr/wu fragments persist in 96
// VGPRs. Phase 1 = r only (critical chain); phase 2 = U-matmul on (r*h)
// PLUS z-matmul on the old h buffer (double-buffered hfrag) -> each barrier
// window has a mixed MFMA/VALU diet so the 4 waves/SIMD overlap pipes.
__global__ __launch_bounds__(1024, 1) void gru_rec(
    const __bf16* __restrict__ afrag, const __bf16* __restrict__ gates,
    const float* __restrict__ h0, float* __restrict__ out)
{
  __shared__ bf16x8 hfA[512];      // [kblk(8)][lane(64)] B-fragment order
  __shared__ bf16x8 hfB[512];
  __shared__ bf16x8 rhf[512];
  int g = blockIdx.x;
  int tid = threadIdx.x;
  int l = tid & 63, w = tid >> 6;   // w in [0,16)
  int q = l >> 4, m15 = l & 15;

  // persistent weight A-fragments for colblock w (96 VGPRs)
  bf16x8 wz_[8], wr_[8], wu_[8];
  const bf16x8* af = (const bf16x8*)afrag;
#pragma unroll
  for (int kb = 0; kb < 8; kb++) {
    wz_[kb] = af[((3 * 16 + w) * 8 + kb) * 64 + l];
    wr_[kb] = af[((4 * 16 + w) * 8 + kb) * 64 + l];
    wu_[kb] = af[((5 * 16 + w) * 8 + kb) * 64 + l];
  }

  // h state: this lane owns batch m15, features 16w+4q+i
  f32x4 hreg;
#pragma unroll
  for (int i = 0; i < 4; i++) hreg[i] = h0[16 * w + 4 * q + i];

  // init hfA (B-fragment of h0, broadcast over batch); waves 0-7 fill
  if (w < 8) {
    const float* hp = h0 + w * 32 + q * 8;
    bf16x8 hv;
#pragma unroll
    for (int j = 0; j < 8; j++) hv[j] = (__bf16)hp[j];
    hfA[w * 64 + l] = hv;
  }
  LDS_BARRIER();

  // packed LDS write slot (bf16x4 units) for features 16w+4q, batch m15:
  // kblk = w>>1, lane' = m15 + 16*((2w+(q>>1))&3), half = q&1
  int slot = (w >> 1) * 128 + (m15 + 16 * ((2 * w + (q >> 1)) & 3)) * 2 + (q & 1);
  bf16x4* rh4 = (bf16x4*)rhf;
  bf16x4* hA4 = (bf16x4*)hfA;
  bf16x4* hB4 = (bf16x4*)hfB;

  const int GSTRIDE = 4 * 12288;
  const __bf16* gt_p = gates + (size_t)g * 12288;
  int go_z = ((0 * 8 + (w >> 1)) * 64 + l) * 8 + (w & 1) * 4;
  int go_r = ((1 * 8 + (w >> 1)) * 64 + l) * 8 + (w & 1) * 4;
  int go_h = ((2 * 8 + (w >> 1)) * 64 + l) * 8 + (w & 1) * 4;
  const float* out_t = out;
  int oo = (g * 16 + m15) * 256 + 16 * w + 4 * q;

  // prefetch t=0 r-gates
  u32x2 gru = *(const u32x2*)(gt_p + go_r);

#pragma unroll 1
  for (int t = 0; t < T_STEPS; t += 2) {
    // ---------------- sub-step A: read hfA, write hfB ----------------
    {
      u32x2 gzu = *(const u32x2*)(gt_p + go_z);
      u32x2 ghu = *(const u32x2*)(gt_p + go_h);
      *(f32x4*)(out_t + oo) = hreg;          // out[t] = pre-update hidden
      out_t += 64 * 256;

      // phase 1: r
      f32x4 ar = {bf_lo(gru.x), bf_hi(gru.x), bf_lo(gru.y), bf_hi(gru.y)};
#pragma unroll
      for (int kb = 0; kb < 8; kb++) ar = MFMA(wr_[kb], hfA[kb * 64 + l], ar);
      f32x4 hd; bf16x4 rhb;
#pragma unroll
      for (int i = 0; i < 4; i++) {
        float r = fast_sigmoid(ar[i]);
        float rh = r * hreg[i];
        hd[i] = hreg[i] - rh;                // (1-r)*h, per reference's (1-r)
        rhb[i] = (__bf16)rh;
      }
      rh4[slot] = rhb;
      gt_p += GSTRIDE;                       // t+1 always valid here
      gru = *(const u32x2*)(gt_p + go_r);    // prefetch next r
      LDS_BARRIER();

      // phase 2: U on rh + z on old h (hfA), combine, write h' to hfB
      f32x4 ah = {bf_lo(ghu.x), bf_hi(ghu.x), bf_lo(ghu.y), bf_hi(ghu.y)};
      f32x4 az = {bf_lo(gzu.x), bf_hi(gzu.x), bf_lo(gzu.y), bf_hi(gzu.y)};
#pragma unroll
      for (int kb = 0; kb < 8; kb++) {
        az = MFMA(wz_[kb], hfA[kb * 64 + l], az);
        ah = MFMA(wu_[kb], rhf[kb * 64 + l], ah);
      }
      bf16x4 nh;
#pragma unroll
      for (int i = 0; i < 4; i++) {
        float z = fast_sigmoid(az[i]);
        float hb = fast_tanh(ah[i]);
        hreg[i] = fmaf(z, hb, hd[i]);
        nh[i] = (__bf16)hreg[i];
      }
      hB4[slot] = nh;
      LDS_BARRIER();
    }
    // ---------------- sub-step B: read hfB, write hfA ----------------
    {
      u32x2 gzu = *(const u32x2*)(gt_p + go_z);
      u32x2 ghu = *(const u32x2*)(gt_p + go_h);
      *(f32x4*)(out_t + oo) = hreg;          // out[t+1]
      out_t += 64 * 256;

      f32x4 ar = {bf_lo(gru.x), bf_hi(gru.x), bf_lo(gru.y), bf_hi(gru.y)};
#pragma unroll
      for (int kb = 0; kb < 8; kb++) ar = MFMA(wr_[kb], hfB[kb * 64 + l], ar);
      f32x4 hd; bf16x4 rhb;
#pragma unroll
      for (int i = 0; i < 4; i++) {
        float r = fast_sigmoid(ar[i]);
        float rh = r * hreg[i];
        hd[i] = hreg[i] - rh;
        rhb[i] = (__bf16)rh;
      }
      rh4[slot] = rhb;
      gt_p += (t + 2 < T_STEPS) ? GSTRIDE : 0;   // clamp at the end
      gru = *(const u32x2*)(gt_p + go_r);
      LDS_BARRIER();

      f32x4 ah = {bf_lo(ghu.x), bf_hi(ghu.x), bf_lo(ghu.y), bf_hi(ghu.y)};
      f32x4 az = {bf_lo(gzu.x), bf_hi(gzu.x), bf_lo(gzu.y), bf_hi(gzu.y)};
#pragma unroll
      for (int kb = 0; kb < 8; kb++) {
        az = MFMA(wz_[kb], hfB[kb * 64 + l], az);
        ah = MFMA(wu_[kb], rhf[kb * 64 + l], ah);
      }
      bf16x4 nh;
#pragma unroll
      for (int i = 0; i < 4; i++) {
        float z = fast_sigmoid(az[i]);
        float hb = fast_tanh(ah[i]);
        hreg[i] = fmaf(z, hb, hd[i]);
        nh[i] = (__bf16)hreg[i];
      }
      hA4[slot] = nh;
      LDS_BARRIER();
    }
  }
}

extern "C" void kernel_launch(void* const* d_in, const int* in_sizes, int n_in,
                              void* d_out, int out_size, void* d_ws, size_t ws_size,
                              hipStream_t stream)
{
  const float* x  = (const float*)d_in[0];
  const float* Wh = (const float*)d_in[1];
  const float* Uh = (const float*)d_in[2];
  const float* bh = (const float*)d_in[3];
  const float* Wr = (const float*)d_in[4];
  const float* Ur = (const float*)d_in[5];
  const float* br = (const float*)d_in[6];
  const float* Wz = (const float*)d_in[7];
  const float* Uz = (const float*)d_in[8];
  const float* bz = (const float*)d_in[9];
  const float* h0 = (const float*)d_in[10];

  __bf16* afrag = (__bf16*)d_ws;
  __bf16* gates = (__bf16*)d_ws + 393216;
  if (ws_size < (size_t)(393216 + 50331648) * 2) return;  // need ~96.8 MB

  prep_frags<<<1536, 256, 0, stream>>>(Wz, Wr, Wh, Uz, Ur, Uh, afrag);
  gemm_x<<<1024, 256, 0, stream>>>(x, afrag, bz, br, bh, gates);
  gru_rec<<<4, 1024, 0, stream>>>(afrag, gates, h0, (float*)d_out);
}